// Round 1
// baseline (626.025 us; speedup 1.0000x reference)
//
#include <hip/hip_runtime.h>
#include <math.h>

// Problem constants
#define BATCH 2
#define SEQ   2048
#define DIM   1024
#define RANK  256
#define HEADS 16
#define HS    16      // RANK/HEADS
#define DH    64      // DIM/HEADS
#define MROWS (BATCH*SEQ)   // 4096

// ---------------- GEMM: C[M][Nc] = A[M][K] * W[Nc][K]^T  (fp32) ----------------
#define BM 64
#define BN 64
#define BKK 16

__global__ __launch_bounds__(256) void gemm_bt_f32(const float* __restrict__ A,
                                                   const float* __restrict__ W,
                                                   float* __restrict__ C,
                                                   int M, int Nc, int K)
{
    // Transposed LDS tiles: As[k][m], pad +4 keeps float4 alignment (stride 68 floats = 272B)
    __shared__ float As[BKK][BM + 4];
    __shared__ float Ws[BKK][BN + 4];

    const int tid = threadIdx.x;
    const int tx = tid & 15;        // 0..15 -> output col group
    const int ty = tid >> 4;        // 0..15 -> output row group
    const int bm = blockIdx.x * BM;
    const int bn = blockIdx.y * BN;

    // loader mapping: each thread loads one float4 of A and one of W per K-tile
    const int lr = tid >> 2;        // 0..63 tile row
    const int lc = (tid & 3) << 2;  // 0,4,8,12 k offset

    float acc[4][4] = {};

    for (int k0 = 0; k0 < K; k0 += BKK) {
        float4 av = *(const float4*)&A[(size_t)(bm + lr) * K + k0 + lc];
        float4 wv = *(const float4*)&W[(size_t)(bn + lr) * K + k0 + lc];
        __syncthreads();   // protect previous iteration's LDS reads
        As[lc + 0][lr] = av.x; As[lc + 1][lr] = av.y; As[lc + 2][lr] = av.z; As[lc + 3][lr] = av.w;
        Ws[lc + 0][lr] = wv.x; Ws[lc + 1][lr] = wv.y; Ws[lc + 2][lr] = wv.z; Ws[lc + 3][lr] = wv.w;
        __syncthreads();

        #pragma unroll
        for (int kk = 0; kk < BKK; ++kk) {
            float4 a4 = *(const float4*)&As[kk][ty * 4];   // ds_read_b128, broadcast
            float4 w4 = *(const float4*)&Ws[kk][tx * 4];   // ds_read_b128, 2-way (free)
            float a[4] = {a4.x, a4.y, a4.z, a4.w};
            float w[4] = {w4.x, w4.y, w4.z, w4.w};
            #pragma unroll
            for (int i = 0; i < 4; ++i)
                #pragma unroll
                for (int j = 0; j < 4; ++j)
                    acc[i][j] = fmaf(a[i], w[j], acc[i][j]);
        }
    }

    #pragma unroll
    for (int i = 0; i < 4; ++i) {
        float4 o = make_float4(acc[i][0], acc[i][1], acc[i][2], acc[i][3]);
        *(float4*)&C[(size_t)(bm + ty * 4 + i) * Nc + bn + tx * 4] = o;
    }
}

// ---------------- L2 normalize q (cols 0..255) and k (cols 256..511) per row ----------------
__global__ __launch_bounds__(256) void l2norm_qk(float* __restrict__ qk)
{
    const int row = blockIdx.x;
    const int t = threadIdx.x;
    float* p = qk + (size_t)row * 512;

    float qv = p[t];
    float kv = p[t + 256];
    float sq = qv * qv;
    float sk = kv * kv;

    #pragma unroll
    for (int off = 32; off > 0; off >>= 1) {
        sq += __shfl_down(sq, off);
        sk += __shfl_down(sk, off);
    }
    __shared__ float sh[8];
    const int wid = t >> 6;
    if ((t & 63) == 0) { sh[wid * 2] = sq; sh[wid * 2 + 1] = sk; }
    __syncthreads();
    sq = sh[0] + sh[2] + sh[4] + sh[6];
    sk = sh[1] + sh[3] + sh[5] + sh[7];

    const float rq = 1.0f / fmaxf(sqrtf(sq), 1e-6f);
    const float rk = 1.0f / fmaxf(sqrtf(sk), 1e-6f);
    p[t]       = qv * rq;
    p[t + 256] = kv * rk;
}

// ---------------- Flash causal attention (fp32) ----------------
// grid: (SEQ/64, HEADS, BATCH), block 256. 4 threads per query row.
__global__ __launch_bounds__(256) void attn_flash(const float* __restrict__ qk,
                                                  const float* __restrict__ v,
                                                  float* __restrict__ out)
{
    const int qt = blockIdx.x;
    const int h  = blockIdx.y;
    const int b  = blockIdx.z;
    const int tid = threadIdx.x;
    const int r = tid >> 2;          // local query row 0..63
    const int c = tid & 3;           // quarter (16 keys / 16 dh elems each)
    const int rg = qt * 64 + r;      // global query index in sequence
    const size_t rowbase = (size_t)b * SEQ + rg;

    __shared__ float K_lds[64][16];
    __shared__ float V_lds[64][68];  // pad 68: 272B rows keep b128 alignment, 2-way banks
    __shared__ float P_lds[64][68];

    // Q row -> registers (duplicated across the 4 c-threads of a row)
    float qreg[16];
    {
        const float* qp = qk + rowbase * 512 + h * HS;
        #pragma unroll
        for (int q4 = 0; q4 < 4; ++q4) {
            float4 t4 = ((const float4*)qp)[q4];
            qreg[q4 * 4 + 0] = t4.x; qreg[q4 * 4 + 1] = t4.y;
            qreg[q4 * 4 + 2] = t4.z; qreg[q4 * 4 + 3] = t4.w;
        }
    }

    float acc[16] = {};
    float mrun = -1e30f, lrun = 0.0f;

    for (int kt = 0; kt <= qt; ++kt) {
        const int k0 = kt * 64;

        // ---- stage K tile [64][16] and V tile [64][64] ----
        {
            const int kk = tid >> 2;
            const int d  = (tid & 3) << 2;
            float4 kv4 = *(const float4*)&qk[((size_t)b * SEQ + k0 + kk) * 512 + 256 + h * HS + d];
            const int j0 = (tid & 3) << 4;
            const float* vp = &v[((size_t)b * SEQ + k0 + kk) * DIM + h * DH + j0];
            float4 v0 = ((const float4*)vp)[0];
            float4 v1 = ((const float4*)vp)[1];
            float4 v2 = ((const float4*)vp)[2];
            float4 v3 = ((const float4*)vp)[3];
            __syncthreads();   // previous tile's LDS reads done
            *(float4*)&K_lds[kk][d] = kv4;
            *(float4*)&V_lds[kk][j0]      = v0;
            *(float4*)&V_lds[kk][j0 + 4]  = v1;
            *(float4*)&V_lds[kk][j0 + 8]  = v2;
            *(float4*)&V_lds[kk][j0 + 12] = v3;
        }
        __syncthreads();

        // ---- scores for 16 keys (interleaved: key = i*4 + c) ----
        float p[16];
        float pmax = -1e30f;
        #pragma unroll
        for (int i = 0; i < 16; ++i) {
            const int kl = i * 4 + c;
            float4 ka = *(const float4*)&K_lds[kl][0];
            float4 kb = *(const float4*)&K_lds[kl][4];
            float4 kc = *(const float4*)&K_lds[kl][8];
            float4 kd = *(const float4*)&K_lds[kl][12];
            float s = qreg[0]*ka.x + qreg[1]*ka.y + qreg[2]*ka.z + qreg[3]*ka.w
                    + qreg[4]*kb.x + qreg[5]*kb.y + qreg[6]*kb.z + qreg[7]*kb.w
                    + qreg[8]*kc.x + qreg[9]*kc.y + qreg[10]*kc.z + qreg[11]*kc.w
                    + qreg[12]*kd.x + qreg[13]*kd.y + qreg[14]*kd.z + qreg[15]*kd.w;
            s *= 0.25f;                                  // SCALE = 1/sqrt(16)
            s = fminf(fmaxf(s, -10000.0f), 10000.0f);    // reference clip
            if (k0 + kl > rg) s = -1e9f;                 // causal mask
            p[i] = s;
            pmax = fmaxf(pmax, s);
        }
        // row max across the 4 c-threads
        pmax = fmaxf(pmax, __shfl_xor(pmax, 1));
        pmax = fmaxf(pmax, __shfl_xor(pmax, 2));

        const float mnew = fmaxf(mrun, pmax);
        const float f = __expf(mrun - mnew);
        float lsum = 0.0f;
        #pragma unroll
        for (int i = 0; i < 16; ++i) {
            p[i] = __expf(p[i] - mnew);
            lsum += p[i];
        }
        lsum += __shfl_xor(lsum, 1);
        lsum += __shfl_xor(lsum, 2);
        lrun = lrun * f + lsum;
        mrun = mnew;
        #pragma unroll
        for (int j = 0; j < 16; ++j) acc[j] *= f;

        // publish P
        #pragma unroll
        for (int i = 0; i < 16; ++i) P_lds[r][i * 4 + c] = p[i];
        __syncthreads();

        // ---- PV: acc[j] += sum_key P[r][key] * V[key][c*16+j] ----
        #pragma unroll
        for (int k4 = 0; k4 < 16; ++k4) {
            float4 p4 = *(const float4*)&P_lds[r][k4 * 4];
            float pu[4] = {p4.x, p4.y, p4.z, p4.w};
            #pragma unroll
            for (int u = 0; u < 4; ++u) {
                const float* vr = &V_lds[k4 * 4 + u][c * 16];
                float4 va = ((const float4*)vr)[0];
                float4 vb = ((const float4*)vr)[1];
                float4 vc = ((const float4*)vr)[2];
                float4 vd = ((const float4*)vr)[3];
                acc[0]  = fmaf(pu[u], va.x, acc[0]);
                acc[1]  = fmaf(pu[u], va.y, acc[1]);
                acc[2]  = fmaf(pu[u], va.z, acc[2]);
                acc[3]  = fmaf(pu[u], va.w, acc[3]);
                acc[4]  = fmaf(pu[u], vb.x, acc[4]);
                acc[5]  = fmaf(pu[u], vb.y, acc[5]);
                acc[6]  = fmaf(pu[u], vb.z, acc[6]);
                acc[7]  = fmaf(pu[u], vb.w, acc[7]);
                acc[8]  = fmaf(pu[u], vc.x, acc[8]);
                acc[9]  = fmaf(pu[u], vc.y, acc[9]);
                acc[10] = fmaf(pu[u], vc.z, acc[10]);
                acc[11] = fmaf(pu[u], vc.w, acc[11]);
                acc[12] = fmaf(pu[u], vd.x, acc[12]);
                acc[13] = fmaf(pu[u], vd.y, acc[13]);
                acc[14] = fmaf(pu[u], vd.z, acc[14]);
                acc[15] = fmaf(pu[u], vd.w, acc[15]);
            }
        }
        // next iteration's staging has its own leading __syncthreads()
    }

    // epilogue: divide by softmax denom, store y[b, n, h, dh]
    const float inv = 1.0f / fmaxf(lrun, 1e-6f);
    float* op = out + rowbase * DIM + h * DH + c * 16;
    #pragma unroll
    for (int q4 = 0; q4 < 4; ++q4) {
        float4 o = make_float4(acc[q4 * 4 + 0] * inv, acc[q4 * 4 + 1] * inv,
                               acc[q4 * 4 + 2] * inv, acc[q4 * 4 + 3] * inv);
        ((float4*)op)[q4] = o;
    }
}

extern "C" void kernel_launch(void* const* d_in, const int* in_sizes, int n_in,
                              void* d_out, int out_size, void* d_ws, size_t ws_size,
                              hipStream_t stream)
{
    const float* x   = (const float*)d_in[0];
    // d_in[1] = mask (causal, implemented analytically)
    const float* Wqk = (const float*)d_in[2];
    const float* Wv  = (const float*)d_in[3];
    float* out = (float*)d_out;

    float* qk = (float*)d_ws;                       // [4096][512]  (q | k), 8 MB
    float* v  = qk + (size_t)MROWS * 2 * RANK;      // [4096][1024], 16 MB

    dim3 g1(MROWS / BM, (2 * RANK) / BN);
    dim3 g2(MROWS / BM, DIM / BN);
    hipLaunchKernelGGL(gemm_bt_f32, g1, dim3(256), 0, stream, x, Wqk, qk, MROWS, 2 * RANK, DIM);
    hipLaunchKernelGGL(gemm_bt_f32, g2, dim3(256), 0, stream, x, Wv, v, MROWS, DIM, DIM);
    hipLaunchKernelGGL(l2norm_qk, dim3(MROWS), dim3(256), 0, stream, qk);
    hipLaunchKernelGGL(attn_flash, dim3(SEQ / 64, HEADS, BATCH), dim3(256), 0, stream, qk, v, out);
}

// Round 2
// 200.656 us; speedup vs baseline: 3.1199x; 3.1199x over previous
//
#include <hip/hip_runtime.h>
#include <math.h>

// Problem constants
#define BATCH 2
#define SEQ   2048
#define DIM   1024
#define RANK  256
#define HEADS 16
#define HS    16      // RANK/HEADS
#define DH    64      // DIM/HEADS
#define MROWS 4096    // BATCH*SEQ
#define NCAT  1536    // 2*RANK + DIM (concatenated GEMM N)

typedef __attribute__((ext_vector_type(8))) short short8;  // 8 bf16 (MFMA A/B frag)
typedef __attribute__((ext_vector_type(4))) float f32x4;   // MFMA C/D frag

__device__ __forceinline__ unsigned short f2bf(float f) {
    union { float f; unsigned u; } v; v.f = f;
    return (unsigned short)((v.u + 0x7FFFu + ((v.u >> 16) & 1u)) >> 16);  // RNE
}
__device__ __forceinline__ float bf2f(unsigned short h) {
    union { unsigned u; float f; } v; v.u = ((unsigned)h) << 16;
    return v.f;
}

// ---------------- f32 -> bf16 convert (4 elems/thread) ----------------
__global__ __launch_bounds__(256) void conv_bf16(const float* __restrict__ in,
                                                 unsigned short* __restrict__ out, int n4) {
    int i = blockIdx.x * 256 + threadIdx.x;
    if (i >= n4) return;
    float4 v = ((const float4*)in)[i];
    ushort4 o; o.x = f2bf(v.x); o.y = f2bf(v.y); o.z = f2bf(v.z); o.w = f2bf(v.w);
    ((ushort4*)out)[i] = o;
}

// ---------------- Combined MFMA GEMM ----------------
// C = A[4096][1024] * Wcat[1536][1024]^T. Columns 0..511 -> qkb (bf16, row-major),
// columns 512..1535 -> vt (bf16, TRANSPOSED [b][d][n] so attention B-frags are contiguous).
// m97 structure: 128x128 tile, BK=32, 4 waves (2x2), global_load_lds width 16.
__global__ __launch_bounds__(256) void gemm_mfma(const unsigned short* __restrict__ A,
                                                 const unsigned short* __restrict__ W,
                                                 unsigned short* __restrict__ qkb,
                                                 unsigned short* __restrict__ vt)
{
    __shared__ __align__(16) unsigned short Alds[128 * 32];
    __shared__ __align__(16) unsigned short Blds[128 * 32];

    const int tid = threadIdx.x;
    const int w = tid >> 6, lane = tid & 63;
    const int lr = lane & 15, lg = lane >> 4;
    const int wm = w >> 1, wn = w & 1;
    const int bm = blockIdx.x * 128, bn = blockIdx.y * 128;

    const int srow = lane >> 2;        // staging row within 16-row chunk
    const int sk   = (lane & 3) * 8;   // staging k offset (bf16 elems)

    f32x4 acc[4][4] = {};

    for (int k0 = 0; k0 < 1024; k0 += 32) {
        __syncthreads();  // previous compute done before LDS overwrite
        #pragma unroll
        for (int q = 0; q < 2; ++q) {
            const int r = (w * 2 + q) * 16 + srow;
            __builtin_amdgcn_global_load_lds(
                (const __attribute__((address_space(1))) unsigned int*)&A[(size_t)(bm + r) * 1024 + k0 + sk],
                (__attribute__((address_space(3))) unsigned int*)&Alds[(w * 2 + q) * 512],
                16, 0, 0);
            __builtin_amdgcn_global_load_lds(
                (const __attribute__((address_space(1))) unsigned int*)&W[(size_t)(bn + r) * 1024 + k0 + sk],
                (__attribute__((address_space(3))) unsigned int*)&Blds[(w * 2 + q) * 512],
                16, 0, 0);
        }
        __syncthreads();  // compiler drains vmcnt(0) before barrier -> staging complete

        short8 af[4], bfr[4];
        #pragma unroll
        for (int mi = 0; mi < 4; ++mi)
            af[mi] = *(const short8*)&Alds[(wm * 64 + mi * 16 + lr) * 32 + lg * 8];
        #pragma unroll
        for (int ni = 0; ni < 4; ++ni)
            bfr[ni] = *(const short8*)&Blds[(wn * 64 + ni * 16 + lr) * 32 + lg * 8];
        #pragma unroll
        for (int mi = 0; mi < 4; ++mi)
            #pragma unroll
            for (int ni = 0; ni < 4; ++ni)
                acc[mi][ni] = __builtin_amdgcn_mfma_f32_16x16x32_bf16(af[mi], bfr[ni], acc[mi][ni], 0, 0, 0);
    }

    // D-frag mapping: col = lane&15, row = 4*(lane>>4)+reg  [m89-verified]
    if (bn < 512) {
        // qk output: bf16 row-major [4096][512]
        #pragma unroll
        for (int mi = 0; mi < 4; ++mi) {
            const int rbase = bm + wm * 64 + mi * 16 + lg * 4;
            #pragma unroll
            for (int ni = 0; ni < 4; ++ni) {
                const int col = bn + wn * 64 + ni * 16 + lr;
                #pragma unroll
                for (int r = 0; r < 4; ++r)
                    qkb[(size_t)(rbase + r) * 512 + col] = f2bf(acc[mi][ni][r]);
            }
        }
    } else {
        // v output: bf16 transposed vt[b][d][n], pack 4 consecutive seq rows per lane
        const int nb = bn - 512;
        #pragma unroll
        for (int mi = 0; mi < 4; ++mi) {
            const int m = bm + wm * 64 + mi * 16 + lg * 4;  // global row (b*SEQ + nseq)
            const int bb = m >> 11, ms = m & 2047;
            #pragma unroll
            for (int ni = 0; ni < 4; ++ni) {
                const int d = nb + wn * 64 + ni * 16 + lr;  // 0..1023
                ushort4 pk;
                pk.x = f2bf(acc[mi][ni][0]); pk.y = f2bf(acc[mi][ni][1]);
                pk.z = f2bf(acc[mi][ni][2]); pk.w = f2bf(acc[mi][ni][3]);
                *(ushort4*)&vt[((size_t)bb * DIM + d) * SEQ + ms] = pk;
            }
        }
    }
}

// ---------------- Full-rank L2 normalize, split q/k, emit bf16 ----------------
__global__ __launch_bounds__(256) void l2norm_split(const unsigned short* __restrict__ qkb,
                                                    unsigned short* __restrict__ qn,
                                                    unsigned short* __restrict__ kn)
{
    const int row = blockIdx.x;
    const int t = threadIdx.x;
    const unsigned short* p = qkb + (size_t)row * 512;
    float q = bf2f(p[t]);
    float k = bf2f(p[t + 256]);
    float sq = q * q, sk = k * k;
    #pragma unroll
    for (int off = 32; off > 0; off >>= 1) {
        sq += __shfl_down(sq, off);
        sk += __shfl_down(sk, off);
    }
    __shared__ float sh[8];
    const int wid = t >> 6;
    if ((t & 63) == 0) { sh[wid * 2] = sq; sh[wid * 2 + 1] = sk; }
    __syncthreads();
    sq = sh[0] + sh[2] + sh[4] + sh[6];
    sk = sh[1] + sh[3] + sh[5] + sh[7];
    const float rq = 1.0f / fmaxf(sqrtf(sq), 1e-6f);
    const float rk = 1.0f / fmaxf(sqrtf(sk), 1e-6f);
    qn[(size_t)row * 256 + t] = f2bf(q * rq);
    kn[(size_t)row * 256 + t] = f2bf(k * rk);
}

// ---------------- MFMA flash attention ----------------
// grid (32, HEADS, BATCH), 256 threads = 4 waves. Wave w owns 16 q-rows; swapped
// QK^T (mfma(K,Q)) puts a full q-row's scores in one lane -> softmax = 2 shfl_xor.
// P goes through wave-PRIVATE LDS (no barriers: DS pipe is in-order per wave).
__global__ __launch_bounds__(256) void attn_mfma(const unsigned short* __restrict__ qn,
                                                 const unsigned short* __restrict__ kn,
                                                 const unsigned short* __restrict__ vt,
                                                 float* __restrict__ out)
{
    const int qt = blockIdx.x, h = blockIdx.y, b = blockIdx.z;
    const int tid = threadIdx.x, w = tid >> 6, lane = tid & 63;
    const int lr = lane & 15, lg = lane >> 4;
    const int qbase = qt * 64 + w * 16;
    const int qrow = qbase + lr;           // this lane's q row (swapped layout)

    // stride 72 bf16 = 144 B: keeps 16B alignment of [row][8k] reads, breaks pow-2 banks
    __shared__ __align__(16) unsigned short P_lds[4][16][72];

    // Q B-frag: col = q-row (lr), k = feature 8*lg+e; features 16..31 are zero pad
    short8 bq = {};
    if (lg < 2)
        bq = *(const short8*)&qn[((size_t)b * SEQ + qbase + lr) * RANK + h * HS + lg * 8];

    f32x4 oacc[4] = {};
    float mrow = -1e30f, lrow = 0.0f;
    const f32x4 zf = {};

    for (int kt = 0; kt <= qt; ++kt) {
        const int k0 = kt * 64;

        // S^T = K*Q^T: 4 MFMAs (16 keys each), K padded 16->32
        f32x4 s[4];
        #pragma unroll
        for (int kg = 0; kg < 4; ++kg) {
            short8 ak = {};
            if (lg < 2)
                ak = *(const short8*)&kn[((size_t)b * SEQ + k0 + kg * 16 + lr) * RANK + h * HS + lg * 8];
            s[kg] = __builtin_amdgcn_mfma_f32_16x16x32_bf16(ak, bq, zf, 0, 0, 0);
        }

        // lane holds S[q=qrow][key = k0 + kg*16 + 4*lg + r]
        float pv[4][4];
        float pmax = -1e30f;
        #pragma unroll
        for (int kg = 0; kg < 4; ++kg)
            #pragma unroll
            for (int r = 0; r < 4; ++r) {
                const int key = k0 + kg * 16 + 4 * lg + r;
                float sv = s[kg][r] * 0.25f;            // SCALE = 1/sqrt(16); |s|<=0.25 so clip is a no-op
                sv = (key > qrow) ? -1e9f : sv;         // causal mask
                pv[kg][r] = sv;
                pmax = fmaxf(pmax, sv);
            }
        pmax = fmaxf(pmax, __shfl_xor(pmax, 16));
        pmax = fmaxf(pmax, __shfl_xor(pmax, 32));

        const float mnew = fmaxf(mrow, pmax);
        const float fsc = __expf(mrow - mnew);
        mrow = mnew;
        float ls = 0.0f;
        #pragma unroll
        for (int kg = 0; kg < 4; ++kg)
            #pragma unroll
            for (int r = 0; r < 4; ++r) {
                const float e = __expf(pv[kg][r] - mnew);
                pv[kg][r] = e;
                ls += e;
            }
        ls += __shfl_xor(ls, 16);
        ls += __shfl_xor(ls, 32);
        lrow = lrow * fsc + ls;

        // rescale O: O-frag rows are q = 4*lg + r; fetch that row's factor from lane (4*lg+r)
        #pragma unroll
        for (int r = 0; r < 4; ++r) {
            const float fr = __shfl(fsc, 4 * lg + r);
            #pragma unroll
            for (int d = 0; d < 4; ++d) oacc[d][r] *= fr;
        }

        // publish P (bf16): keys kg*16+4*lg..+3 are contiguous -> one 8B store per kg
        #pragma unroll
        for (int kg = 0; kg < 4; ++kg) {
            ushort4 pk;
            pk.x = f2bf(pv[kg][0]); pk.y = f2bf(pv[kg][1]);
            pk.z = f2bf(pv[kg][2]); pk.w = f2bf(pv[kg][3]);
            *(ushort4*)&P_lds[w][lr][kg * 16 + 4 * lg] = pk;
        }
        // wave-private LDS + in-order DS pipe: no barrier needed; compiler inserts lgkmcnt

        // PV: O[q][dh] += P[q][key] * V[key][dh]; V B-frags contiguous from vt[b][d][n]
        #pragma unroll
        for (int c = 0; c < 2; ++c) {
            const short8 pa = *(const short8*)&P_lds[w][lr][c * 32 + lg * 8];
            #pragma unroll
            for (int d = 0; d < 4; ++d) {
                const short8 bv = *(const short8*)&vt[((size_t)b * DIM + h * DH + d * 16 + lr) * SEQ + k0 + c * 32 + lg * 8];
                oacc[d] = __builtin_amdgcn_mfma_f32_16x16x32_bf16(pa, bv, oacc[d], 0, 0, 0);
            }
        }
    }

    // epilogue: O-frag rows are q = 4*lg + r; fetch denom from lane (4*lg+r)
    #pragma unroll
    for (int r = 0; r < 4; ++r) {
        const float lr_row = __shfl(lrow, 4 * lg + r);
        const float inv = 1.0f / fmaxf(lr_row, 1e-6f);
        const size_t obase = ((size_t)b * SEQ + qbase + 4 * lg + r) * DIM + h * DH;
        #pragma unroll
        for (int d = 0; d < 4; ++d)
            out[obase + d * 16 + lr] = oacc[d][r] * inv;
    }
}

extern "C" void kernel_launch(void* const* d_in, const int* in_sizes, int n_in,
                              void* d_out, int out_size, void* d_ws, size_t ws_size,
                              hipStream_t stream)
{
    const float* x   = (const float*)d_in[0];
    // d_in[1] = mask (causal, analytic)
    const float* Wqk = (const float*)d_in[2];
    const float* Wv  = (const float*)d_in[3];
    float* out = (float*)d_out;

    // workspace layout (23 MB): xb 8MB | qkb 4MB | vt 8MB | wcat 3MB
    // qn/kn (4MB) overlay xb after the GEMM (xb dead by then)
    unsigned short* xb   = (unsigned short*)d_ws;
    unsigned short* qkb  = xb  + (size_t)MROWS * DIM;        // 4096*512 bf16
    unsigned short* vt   = qkb + (size_t)MROWS * 512;        // 2*1024*2048 bf16
    unsigned short* wcat = vt  + (size_t)BATCH * DIM * SEQ;  // 1536*1024 bf16
    unsigned short* qn = xb;
    unsigned short* kn = xb + (size_t)MROWS * RANK;

    conv_bf16<<<4096, 256, 0, stream>>>(x,   xb,   MROWS * DIM / 4);
    conv_bf16<<<512,  256, 0, stream>>>(Wqk, wcat, 2 * RANK * DIM / 4);
    conv_bf16<<<1024, 256, 0, stream>>>(Wv,  wcat + (size_t)2 * RANK * DIM, DIM * DIM / 4);
    gemm_mfma<<<dim3(32, 12), 256, 0, stream>>>(xb, wcat, qkb, vt);
    l2norm_split<<<MROWS, 256, 0, stream>>>(qkb, qn, kn);
    attn_mfma<<<dim3(SEQ / 64, HEADS, BATCH), 256, 0, stream>>>(qn, kn, vt, out);
}

// Round 3
// 93.134 us; speedup vs baseline: 6.7217x; 2.1545x over previous
//
#include <hip/hip_runtime.h>
#include <math.h>

// Problem constants
#define BATCH 2
#define SEQ   2048
#define DIM   1024
#define RANK  256
#define HEADS 16
#define HS    16
#define DH    64
#define MROWS 4096

typedef __attribute__((ext_vector_type(8))) short short8;  // 8 bf16 (MFMA A/B frag)
typedef __attribute__((ext_vector_type(4))) float f32x4;   // MFMA C/D frag

__device__ __forceinline__ unsigned short f2bf(float f) {
    union { float f; unsigned u; } v; v.f = f;
    return (unsigned short)((v.u + 0x7FFFu + ((v.u >> 16) & 1u)) >> 16);  // RNE
}
__device__ __forceinline__ float bf2f(unsigned short h) {
    union { unsigned u; float f; } v; v.u = ((unsigned)h) << 16;
    return v.f;
}

// ---------------- f32 -> bf16 convert (4 elems/thread) ----------------
__global__ __launch_bounds__(256) void conv_bf16(const float* __restrict__ in,
                                                 unsigned short* __restrict__ out, int n4) {
    int i = blockIdx.x * 256 + threadIdx.x;
    if (i >= n4) return;
    float4 v = ((const float4*)in)[i];
    ushort4 o; o.x = f2bf(v.x); o.y = f2bf(v.y); o.z = f2bf(v.z); o.w = f2bf(v.w);
    ((ushort4*)out)[i] = o;
}

// ---------------- MFMA GEMM, 128x64 tile (768 blocks = 3/CU) ----------------
// C = A[4096][1024] * Wcat[1536][1024]^T. cols 0..511 -> qkb row-major bf16,
// cols 512..1535 -> vt transposed [b][d][n] bf16.
__global__ __launch_bounds__(256) void gemm_mfma(const unsigned short* __restrict__ A,
                                                 const unsigned short* __restrict__ W,
                                                 unsigned short* __restrict__ qkb,
                                                 unsigned short* __restrict__ vt)
{
    __shared__ __align__(16) unsigned short Alds[128 * 32];
    __shared__ __align__(16) unsigned short Blds[64 * 32];

    const int tid = threadIdx.x;
    const int w = tid >> 6, lane = tid & 63;
    const int lr = lane & 15, lg = lane >> 4;
    const int wm = w >> 1, wn = w & 1;
    const int bm = blockIdx.x * 128, bn = blockIdx.y * 64;

    const int srow = lane >> 2;        // row within 16-row staging chunk
    const int sk   = (lane & 3) * 8;   // k offset (bf16 elems)

    f32x4 acc[4][2] = {};

    for (int k0 = 0; k0 < 1024; k0 += 32) {
        __syncthreads();
        #pragma unroll
        for (int q = 0; q < 2; ++q) {
            const int r = (w * 2 + q) * 16 + srow;
            __builtin_amdgcn_global_load_lds(
                (const __attribute__((address_space(1))) unsigned int*)&A[(size_t)(bm + r) * 1024 + k0 + sk],
                (__attribute__((address_space(3))) unsigned int*)&Alds[(w * 2 + q) * 512],
                16, 0, 0);
        }
        __builtin_amdgcn_global_load_lds(
            (const __attribute__((address_space(1))) unsigned int*)&W[(size_t)(bn + w * 16 + srow) * 1024 + k0 + sk],
            (__attribute__((address_space(3))) unsigned int*)&Blds[w * 512],
            16, 0, 0);
        __syncthreads();

        short8 af[4], bfr[2];
        #pragma unroll
        for (int mi = 0; mi < 4; ++mi)
            af[mi] = *(const short8*)&Alds[(wm * 64 + mi * 16 + lr) * 32 + lg * 8];
        #pragma unroll
        for (int ni = 0; ni < 2; ++ni)
            bfr[ni] = *(const short8*)&Blds[(wn * 32 + ni * 16 + lr) * 32 + lg * 8];
        #pragma unroll
        for (int mi = 0; mi < 4; ++mi)
            #pragma unroll
            for (int ni = 0; ni < 2; ++ni)
                acc[mi][ni] = __builtin_amdgcn_mfma_f32_16x16x32_bf16(af[mi], bfr[ni], acc[mi][ni], 0, 0, 0);
    }

    // D-frag: col = lane&15, row = 4*(lane>>4)+reg
    if (bn < 512) {
        #pragma unroll
        for (int mi = 0; mi < 4; ++mi) {
            const int rbase = bm + wm * 64 + mi * 16 + lg * 4;
            #pragma unroll
            for (int ni = 0; ni < 2; ++ni) {
                const int col = bn + wn * 32 + ni * 16 + lr;
                #pragma unroll
                for (int r = 0; r < 4; ++r)
                    qkb[(size_t)(rbase + r) * 512 + col] = f2bf(acc[mi][ni][r]);
            }
        }
    } else {
        const int nb = bn - 512;
        #pragma unroll
        for (int mi = 0; mi < 4; ++mi) {
            const int m = bm + wm * 64 + mi * 16 + lg * 4;
            const int bb = m >> 11, ms = m & 2047;
            #pragma unroll
            for (int ni = 0; ni < 2; ++ni) {
                const int d = nb + wn * 32 + ni * 16 + lr;
                ushort4 pk;
                pk.x = f2bf(acc[mi][ni][0]); pk.y = f2bf(acc[mi][ni][1]);
                pk.z = f2bf(acc[mi][ni][2]); pk.w = f2bf(acc[mi][ni][3]);
                *(ushort4*)&vt[((size_t)bb * DIM + d) * SEQ + ms] = pk;
            }
        }
    }
}

// ---------------- Full-rank L2 normalize, split q/k ----------------
__global__ __launch_bounds__(256) void l2norm_split(const unsigned short* __restrict__ qkb,
                                                    unsigned short* __restrict__ qn,
                                                    unsigned short* __restrict__ kn)
{
    const int row = blockIdx.x;
    const int t = threadIdx.x;
    const unsigned short* p = qkb + (size_t)row * 512;
    float q = bf2f(p[t]);
    float k = bf2f(p[t + 256]);
    float sq = q * q, sk = k * k;
    #pragma unroll
    for (int off = 32; off > 0; off >>= 1) {
        sq += __shfl_down(sq, off);
        sk += __shfl_down(sk, off);
    }
    __shared__ float sh[8];
    const int wid = t >> 6;
    if ((t & 63) == 0) { sh[wid * 2] = sq; sh[wid * 2 + 1] = sk; }
    __syncthreads();
    sq = sh[0] + sh[2] + sh[4] + sh[6];
    sk = sh[1] + sh[3] + sh[5] + sh[7];
    const float rq = 1.0f / fmaxf(sqrtf(sq), 1e-6f);
    const float rk = 1.0f / fmaxf(sqrtf(sk), 1e-6f);
    qn[(size_t)row * 256 + t] = f2bf(q * rq);
    kn[(size_t)row * 256 + t] = f2bf(k * rk);
}

// ---------------- MFMA flash attention, no-max softmax ----------------
// Scores bounded: |q_h . k_h| <= 1, * 0.25 -> exp(s) in [0.78, 1.28]. Max
// subtraction / clip / NaN guard are provably no-ops -> direct exp, no
// rescale, lsum deferred to epilogue. K/V staged in LDS (double-buffered,
// shared by 4 waves). V XOR-swizzled via pre-swizzled GLOBAL source (linear
// gload_lds dest) + swizzled ds_read: 2-way banks (free).
template<bool MASK>
__device__ __forceinline__ void attn_tile(int k0, int qrow, int lr, int lg,
                                          const short8 bq,
                                          const unsigned short* Kl,
                                          const unsigned short* Vl,
                                          unsigned short (*P)[72],
                                          f32x4 oacc[4], float& lpart)
{
    const f32x4 zf = {};
    f32x4 s[4];
    #pragma unroll
    for (int kg = 0; kg < 4; ++kg) {
        short8 ak = {};
        if (lg < 2) ak = *(const short8*)&Kl[(kg * 16 + lr) * 16 + lg * 8];
        s[kg] = __builtin_amdgcn_mfma_f32_16x16x32_bf16(ak, bq, zf, 0, 0, 0);
    }

    float p[4][4];
    #pragma unroll
    for (int kg = 0; kg < 4; ++kg) {
        #pragma unroll
        for (int r = 0; r < 4; ++r) {
            float e = __expf(s[kg][r] * 0.25f);
            if (MASK) {
                const int key = k0 + kg * 16 + 4 * lg + r;
                e = (key > qrow) ? 0.0f : e;
            }
            p[kg][r] = e;
        }
        lpart += (p[kg][0] + p[kg][1]) + (p[kg][2] + p[kg][3]);
    }

    // pack P to bf16 (cvt_pk) and publish via wave-private LDS (no barrier)
    #pragma unroll
    for (int kg = 0; kg < 4; ++kg) {
        unsigned u0, u1;
        asm("v_cvt_pk_bf16_f32 %0, %1, %2" : "=v"(u0) : "v"(p[kg][0]), "v"(p[kg][1]));
        asm("v_cvt_pk_bf16_f32 %0, %1, %2" : "=v"(u1) : "v"(p[kg][2]), "v"(p[kg][3]));
        uint2 pk2; pk2.x = u0; pk2.y = u1;
        *(uint2*)&P[lr][kg * 16 + 4 * lg] = pk2;
    }

    // PV: O[q][dh] += P[q][key] * V[key][dh]
    #pragma unroll
    for (int c = 0; c < 2; ++c) {
        const short8 pa = *(const short8*)&P[lr][c * 32 + lg * 8];
        #pragma unroll
        for (int d = 0; d < 4; ++d) {
            const int row = d * 16 + lr;
            const int cb = (c * 64 + lg * 16) ^ ((row & 7) << 4);  // swizzled byte col
            const short8 bv = *(const short8*)&Vl[row * 64 + (cb >> 1)];
            oacc[d] = __builtin_amdgcn_mfma_f32_16x16x32_bf16(pa, bv, oacc[d], 0, 0, 0);
        }
    }
}

__global__ __launch_bounds__(256) void attn_mfma(const unsigned short* __restrict__ qn,
                                                 const unsigned short* __restrict__ kn,
                                                 const unsigned short* __restrict__ vt,
                                                 float* __restrict__ out)
{
    const int qt = (int)gridDim.x - 1 - (int)blockIdx.x;  // LPT: heavy tiles first
    const int h = blockIdx.y, b = blockIdx.z;
    const int tid = threadIdx.x, w = tid >> 6, lane = tid & 63;
    const int lr = lane & 15, lg = lane >> 4;
    const int qbase = qt * 64 + w * 16;
    const int qrow = qbase + lr;

    __shared__ __align__(16) unsigned short Kl[2][64 * 16];
    __shared__ __align__(16) unsigned short Vl[2][64 * 64];
    __shared__ __align__(16) unsigned short P_lds[4][16][72];

    // Q B-frag (features 16..31 zero-padded)
    short8 bq = {};
    if (lg < 2)
        bq = *(const short8*)&qn[((size_t)b * SEQ + qrow) * RANK + h * HS + lg * 8];

    f32x4 oacc[4] = {};
    float lpart = 0.0f;

    // staging: wave w -> V chunks {2w, 2w+1}; waves 0,1 -> K chunks
    const int vrow = lane >> 3;                 // 0..7 within V chunk
    const int vsrc = 8 * ((lane & 7) ^ vrow);   // pre-swizzled source col (elems)
    const int krow = lane >> 1;                 // 0..31 within K chunk
    const int ksrc = (lane & 1) * 8;

#define STAGE(kt_, buf_) do {                                                              \
        const int k0_ = (kt_) * 64;                                                        \
        _Pragma("unroll")                                                                  \
        for (int qq = 0; qq < 2; ++qq) {                                                   \
            const int i = w * 2 + qq;                                                      \
            __builtin_amdgcn_global_load_lds(                                              \
                (const __attribute__((address_space(1))) unsigned int*)                    \
                    &vt[((size_t)b * DIM + h * DH + i * 8 + vrow) * SEQ + k0_ + vsrc],     \
                (__attribute__((address_space(3))) unsigned int*)&Vl[buf_][i * 512],       \
                16, 0, 0);                                                                 \
        }                                                                                  \
        if (w < 2) {                                                                       \
            __builtin_amdgcn_global_load_lds(                                              \
                (const __attribute__((address_space(1))) unsigned int*)                    \
                    &kn[((size_t)b * SEQ + k0_ + w * 32 + krow) * RANK + h * HS + ksrc],   \
                (__attribute__((address_space(3))) unsigned int*)&Kl[buf_][w * 512],       \
                16, 0, 0);                                                                 \
        }                                                                                  \
    } while (0)

    STAGE(0, 0);
    __syncthreads();

    for (int kt = 0; kt < qt; ++kt) {
        const int buf = kt & 1;
        STAGE(kt + 1, buf ^ 1);
        attn_tile<false>(kt * 64, qrow, lr, lg, bq, Kl[buf], Vl[buf], P_lds[w], oacc, lpart);
        __syncthreads();  // drains stage vmcnt + all waves past reads of buf
    }
    // diagonal tile (the only one needing the causal mask)
    attn_tile<true>(qt * 64, qrow, lr, lg, bq, Kl[qt & 1], Vl[qt & 1], P_lds[w], oacc, lpart);
#undef STAGE

    // row denominators: reduce over the 4 lg-groups, then distribute
    lpart += __shfl_xor(lpart, 16);
    lpart += __shfl_xor(lpart, 32);

    #pragma unroll
    for (int r = 0; r < 4; ++r) {
        const float ls = __shfl(lpart, 4 * lg + r);
        const float inv = 1.0f / fmaxf(ls, 1e-6f);
        const size_t obase = ((size_t)b * SEQ + qbase + 4 * lg + r) * DIM + h * DH;
        #pragma unroll
        for (int d = 0; d < 4; ++d)
            out[obase + d * 16 + lr] = oacc[d][r] * inv;
    }
}

extern "C" void kernel_launch(void* const* d_in, const int* in_sizes, int n_in,
                              void* d_out, int out_size, void* d_ws, size_t ws_size,
                              hipStream_t stream)
{
    const float* x   = (const float*)d_in[0];
    // d_in[1] = mask (causal, analytic)
    const float* Wqk = (const float*)d_in[2];
    const float* Wv  = (const float*)d_in[3];
    float* out = (float*)d_out;

    // workspace: xb 8MB | qkb 4MB | vt 8MB | wcat 3MB ; qn/kn overlay xb after GEMM
    unsigned short* xb   = (unsigned short*)d_ws;
    unsigned short* qkb  = xb  + (size_t)MROWS * DIM;
    unsigned short* vt   = qkb + (size_t)MROWS * 512;
    unsigned short* wcat = vt  + (size_t)BATCH * DIM * SEQ;
    unsigned short* qn = xb;
    unsigned short* kn = xb + (size_t)MROWS * RANK;

    conv_bf16<<<4096, 256, 0, stream>>>(x,   xb,   MROWS * DIM / 4);
    conv_bf16<<<512,  256, 0, stream>>>(Wqk, wcat, 2 * RANK * DIM / 4);
    conv_bf16<<<1024, 256, 0, stream>>>(Wv,  wcat + (size_t)2 * RANK * DIM, DIM * DIM / 4);
    gemm_mfma<<<dim3(32, 24), 256, 0, stream>>>(xb, wcat, qkb, vt);
    l2norm_split<<<MROWS, 256, 0, stream>>>(qkb, qn, kn);
    attn_mfma<<<dim3(SEQ / 64, HEADS, BATCH), 256, 0, stream>>>(qn, kn, vt, out);
}

// Round 4
// 93.033 us; speedup vs baseline: 6.7290x; 1.0011x over previous
//
#include <hip/hip_runtime.h>
#include <math.h>

// Problem constants
#define BATCH 2
#define SEQ   2048
#define DIM   1024
#define RANK  256
#define HEADS 16
#define HS    16
#define DH    64
#define MROWS 4096

typedef __attribute__((ext_vector_type(8)))  short    short8;   // 8 bf16
typedef __attribute__((ext_vector_type(4)))  float    f32x4;
typedef __attribute__((ext_vector_type(16))) float    f32x16;
typedef __attribute__((ext_vector_type(2)))  unsigned uint2v;

__device__ __forceinline__ unsigned short f2bf(float f) {
    union { float f; unsigned u; } v; v.f = f;
    return (unsigned short)((v.u + 0x7FFFu + ((v.u >> 16) & 1u)) >> 16);  // RNE
}
__device__ __forceinline__ float bf2f(unsigned short h) {
    union { unsigned u; float f; } v; v.u = ((unsigned)h) << 16;
    return v.f;
}

// ---------------- f32 -> bf16 convert ----------------
__global__ __launch_bounds__(256) void conv_bf16(const float* __restrict__ in,
                                                 unsigned short* __restrict__ out, int n4) {
    int i = blockIdx.x * 256 + threadIdx.x;
    if (i >= n4) return;
    float4 v = ((const float4*)in)[i];
    ushort4 o; o.x = f2bf(v.x); o.y = f2bf(v.y); o.z = f2bf(v.z); o.w = f2bf(v.w);
    ((ushort4*)out)[i] = o;
}

// ---------------- MFMA GEMM, 128x64 tile ----------------
__global__ __launch_bounds__(256) void gemm_mfma(const unsigned short* __restrict__ A,
                                                 const unsigned short* __restrict__ W,
                                                 unsigned short* __restrict__ qkb,
                                                 unsigned short* __restrict__ vt)
{
    __shared__ __align__(16) unsigned short Alds[128 * 32];
    __shared__ __align__(16) unsigned short Blds[64 * 32];

    const int tid = threadIdx.x;
    const int w = tid >> 6, lane = tid & 63;
    const int lr = lane & 15, lg = lane >> 4;
    const int wm = w >> 1, wn = w & 1;
    const int bm = blockIdx.x * 128, bn = blockIdx.y * 64;

    const int srow = lane >> 2;
    const int sk   = (lane & 3) * 8;

    f32x4 acc[4][2] = {};

    for (int k0 = 0; k0 < 1024; k0 += 32) {
        __syncthreads();
        #pragma unroll
        for (int q = 0; q < 2; ++q) {
            const int r = (w * 2 + q) * 16 + srow;
            __builtin_amdgcn_global_load_lds(
                (const __attribute__((address_space(1))) unsigned int*)&A[(size_t)(bm + r) * 1024 + k0 + sk],
                (__attribute__((address_space(3))) unsigned int*)&Alds[(w * 2 + q) * 512],
                16, 0, 0);
        }
        __builtin_amdgcn_global_load_lds(
            (const __attribute__((address_space(1))) unsigned int*)&W[(size_t)(bn + w * 16 + srow) * 1024 + k0 + sk],
            (__attribute__((address_space(3))) unsigned int*)&Blds[w * 512],
            16, 0, 0);
        __syncthreads();

        short8 af[4], bfr[2];
        #pragma unroll
        for (int mi = 0; mi < 4; ++mi)
            af[mi] = *(const short8*)&Alds[(wm * 64 + mi * 16 + lr) * 32 + lg * 8];
        #pragma unroll
        for (int ni = 0; ni < 2; ++ni)
            bfr[ni] = *(const short8*)&Blds[(wn * 32 + ni * 16 + lr) * 32 + lg * 8];
        #pragma unroll
        for (int mi = 0; mi < 4; ++mi)
            #pragma unroll
            for (int ni = 0; ni < 2; ++ni)
                acc[mi][ni] = __builtin_amdgcn_mfma_f32_16x16x32_bf16(af[mi], bfr[ni], acc[mi][ni], 0, 0, 0);
    }

    if (bn < 512) {
        #pragma unroll
        for (int mi = 0; mi < 4; ++mi) {
            const int rbase = bm + wm * 64 + mi * 16 + lg * 4;
            #pragma unroll
            for (int ni = 0; ni < 2; ++ni) {
                const int col = bn + wn * 32 + ni * 16 + lr;
                #pragma unroll
                for (int r = 0; r < 4; ++r)
                    qkb[(size_t)(rbase + r) * 512 + col] = f2bf(acc[mi][ni][r]);
            }
        }
    } else {
        const int nb = bn - 512;
        #pragma unroll
        for (int mi = 0; mi < 4; ++mi) {
            const int m = bm + wm * 64 + mi * 16 + lg * 4;
            const int bb = m >> 11, ms = m & 2047;
            #pragma unroll
            for (int ni = 0; ni < 2; ++ni) {
                const int d = nb + wn * 32 + ni * 16 + lr;
                ushort4 pk;
                pk.x = f2bf(acc[mi][ni][0]); pk.y = f2bf(acc[mi][ni][1]);
                pk.z = f2bf(acc[mi][ni][2]); pk.w = f2bf(acc[mi][ni][3]);
                *(ushort4*)&vt[((size_t)bb * DIM + d) * SEQ + ms] = pk;
            }
        }
    }
}

// ---------------- Full-rank L2 normalize, split q/k ----------------
__global__ __launch_bounds__(256) void l2norm_split(const unsigned short* __restrict__ qkb,
                                                    unsigned short* __restrict__ qn,
                                                    unsigned short* __restrict__ kn)
{
    const int row = blockIdx.x;
    const int t = threadIdx.x;
    const unsigned short* p = qkb + (size_t)row * 512;
    float q = bf2f(p[t]);
    float k = bf2f(p[t + 256]);
    float sq = q * q, sk = k * k;
    #pragma unroll
    for (int off = 32; off > 0; off >>= 1) {
        sq += __shfl_down(sq, off);
        sk += __shfl_down(sk, off);
    }
    __shared__ float sh[8];
    const int wid = t >> 6;
    if ((t & 63) == 0) { sh[wid * 2] = sq; sh[wid * 2 + 1] = sk; }
    __syncthreads();
    sq = sh[0] + sh[2] + sh[4] + sh[6];
    sk = sh[1] + sh[3] + sh[5] + sh[7];
    const float rq = 1.0f / fmaxf(sqrtf(sq), 1e-6f);
    const float rk = 1.0f / fmaxf(sqrtf(sk), 1e-6f);
    qn[(size_t)row * 256 + t] = f2bf(q * rq);
    kn[(size_t)row * 256 + t] = f2bf(k * rk);
}

// ---------------- 32x32 MFMA flash attention, in-register P ----------------
// Block = 4 waves = 2 q-bands(32 rows) x 2 k-halves(64 keys of a 128-key tile).
// No-max softmax => kh-partials simply ADD (no rescale coupling). P rebuilt
// in-register via cvt_pk_bf16 + permlane32_swap (lane+-32 exchange).
#define C1EXP 0.36067376f  /* 0.25 * log2(e) */

template<bool MASK>
__device__ __forceinline__ void tile32(const unsigned char* smem, int buf, int k0, int kh,
                                       int l31, int hi, int qg, const short8 bq,
                                       f32x16 o[2], float& lpart)
{
    const unsigned short* Vs = (const unsigned short*)(smem + buf * 16384);
    const unsigned short* Ks = (const unsigned short*)(smem + 32768 + buf * 4096);
    const f32x16 z = {};

    // K A-frags: row = 64*kh + c*32 + l31, feats 8*hi..+7, col-XOR (row&1)
    const int kro = (64 * kh + l31) * 16 + 8 * (hi ^ (l31 & 1));
    const short8 ak0 = *(const short8*)&Ks[kro];
    const short8 ak1 = *(const short8*)&Ks[kro + 32 * 16];
    const f32x16 s0 = __builtin_amdgcn_mfma_f32_32x32x16_bf16(ak0, bq, z, 0, 0, 0);
    const f32x16 s1 = __builtin_amdgcn_mfma_f32_32x32x16_bf16(ak1, bq, z, 0, 0, 0);

    float p0[16], p1[16];
    #pragma unroll
    for (int r = 0; r < 16; ++r) {
        float e0 = __builtin_exp2f(s0[r] * C1EXP);
        float e1 = __builtin_exp2f(s1[r] * C1EXP);
        if (MASK) {
            const int kl = k0 + 64 * kh + (r & 3) + 8 * (r >> 2) + 4 * hi;
            e0 = (kl > qg) ? 0.0f : e0;
            e1 = (kl + 32 > qg) ? 0.0f : e1;
        }
        p0[r] = e0; p1[r] = e1;
        lpart += e0 + e1;
    }

    // rebuild PV A-frags: keys g*16 + 8*hi + e per lane
    short8 pa[4];
    #pragma unroll
    for (int g = 0; g < 4; ++g) {
        const float* pc = (g < 2) ? p0 : p1;
        const int jj = 2 * (g & 1);
        unsigned a0, a1, b0, b1;
        asm("v_cvt_pk_bf16_f32 %0, %1, %2" : "=v"(a0) : "v"(pc[4*jj]),     "v"(pc[4*jj + 1]));
        asm("v_cvt_pk_bf16_f32 %0, %1, %2" : "=v"(b0) : "v"(pc[4*jj + 2]), "v"(pc[4*jj + 3]));
        asm("v_cvt_pk_bf16_f32 %0, %1, %2" : "=v"(a1) : "v"(pc[4*jj + 4]), "v"(pc[4*jj + 5]));
        asm("v_cvt_pk_bf16_f32 %0, %1, %2" : "=v"(b1) : "v"(pc[4*jj + 6]), "v"(pc[4*jj + 7]));
        const uint2v r0 = __builtin_amdgcn_permlane32_swap(a0, a1, false, false);
        const uint2v r1 = __builtin_amdgcn_permlane32_swap(b0, b1, false, false);
        union { short8 s; unsigned u[4]; } pu;
        pu.u[0] = r0[0]; pu.u[1] = r1[0]; pu.u[2] = r0[1]; pu.u[3] = r1[1];
        pa[g] = pu.s;
    }

    // PV: O[q][dh] += P * V ; V rows = dh (XOR-swizzled cols)
    #pragma unroll
    for (int g = 0; g < 4; ++g) {
        #pragma unroll
        for (int half = 0; half < 2; ++half) {
            const int rv = half * 32 + l31;
            const short8 bv = *(const short8*)&Vs[rv * 128 + ((64 * kh + 16 * g + 8 * hi) ^ (8 * (l31 & 7)))];
            o[half] = __builtin_amdgcn_mfma_f32_32x32x16_bf16(pa[g], bv, o[half], 0, 0, 0);
        }
    }
}

__global__ __launch_bounds__(256, 4) void attn_mfma32(const unsigned short* __restrict__ qn,
                                                      const unsigned short* __restrict__ kn,
                                                      const unsigned short* __restrict__ vt,
                                                      float* __restrict__ out)
{
    const int qt = (int)gridDim.x - 1 - (int)blockIdx.x;  // LPT: heavy first
    const int h = blockIdx.y, b = blockIdx.z;
    const int tid = threadIdx.x, w = tid >> 6, lane = tid & 63;
    const int qh = w >> 1, kh = w & 1;
    const int l31 = lane & 31, hi = lane >> 5;
    const int qband = qt * 64 + qh * 32;
    const int qg = qband + l31;

    __shared__ __align__(16) unsigned char smem[40960];  // V 2x16K | K 2x4K

    // Q B-frag: col = q (l31), feats 8*hi..+7
    const short8 bq = *(const short8*)&qn[((size_t)b * SEQ + qg) * RANK + h * HS + 8 * hi];

    f32x16 o[2] = {};
    float lpart = 0.0f;

#define STAGE32(kt_, buf_) do {                                                                   \
        const int k0_ = (kt_) * 128;                                                              \
        unsigned short* Vd = (unsigned short*)(smem + (buf_) * 16384);                            \
        unsigned short* Kd = (unsigned short*)(smem + 32768 + (buf_) * 4096);                     \
        _Pragma("unroll")                                                                         \
        for (int i = 0; i < 4; ++i) {                                                             \
            const int dh = w * 16 + i * 4 + (lane >> 4);                                          \
            const int so = 8 * ((lane & 15) ^ (dh & 7));                                          \
            __builtin_amdgcn_global_load_lds(                                                     \
                (const __attribute__((address_space(1))) unsigned int*)                           \
                    &vt[((size_t)b * DIM + h * DH + dh) * SEQ + k0_ + so],                        \
                (__attribute__((address_space(3))) unsigned int*)&Vd[(w * 4 + i) * 512],          \
                16, 0, 0);                                                                        \
        }                                                                                         \
        {                                                                                         \
            const int row = 32 * w + (lane >> 1);                                                 \
            const int so = 8 * ((lane & 1) ^ ((lane >> 1) & 1));                                  \
            __builtin_amdgcn_global_load_lds(                                                     \
                (const __attribute__((address_space(1))) unsigned int*)                           \
                    &kn[((size_t)b * SEQ + k0_ + row) * RANK + h * HS + so],                      \
                (__attribute__((address_space(3))) unsigned int*)&Kd[w * 512],                    \
                16, 0, 0);                                                                        \
        }                                                                                         \
    } while (0)

    const int ntiles = (qt >> 1) + 1;   // ceil((qt+1)/2) tiles of 128 keys

    STAGE32(0, 0);
    __syncthreads();

    for (int kt = 0; kt < ntiles - 1; ++kt) {
        STAGE32(kt + 1, (kt + 1) & 1);
        tile32<false>(smem, kt & 1, kt * 128, kh, l31, hi, qg, bq, o, lpart);
        __syncthreads();
    }
    {
        const int kt = ntiles - 1;
        const int wfirst = 128 * kt + 64 * kh;
        if (wfirst <= qband + 31) {                    // any unmasked keys?
            if (wfirst + 63 <= qband)                  // fully below all q -> no mask
                tile32<false>(smem, kt & 1, kt * 128, kh, l31, hi, qg, bq, o, lpart);
            else
                tile32<true>(smem, kt & 1, kt * 128, kh, l31, hi, qg, bq, o, lpart);
        }
    }
#undef STAGE32
    __syncthreads();

    // merge kh partials via LDS overlay (staging buffers dead post-barrier)
    float* Osm = (float*)smem;              // [2 bands][32 q][64 dh]
    float* Lsm = (float*)(smem + 16384);    // [2 bands][64 lanes]
    if (kh == 1) {
        #pragma unroll
        for (int half = 0; half < 2; ++half)
            #pragma unroll
            for (int r = 0; r < 16; ++r) {
                const int q = (r & 3) + 8 * (r >> 2) + 4 * hi;
                Osm[(qh * 32 + q) * 64 + half * 32 + l31] = o[half][r];
            }
        Lsm[qh * 64 + lane] = lpart;
    }
    __syncthreads();
    if (kh == 0) {
        float lt = lpart + Lsm[qh * 64 + lane];
        lt += __shfl_xor(lt, 32);
        const float inv = 1.0f / fmaxf(lt, 1e-6f);
        #pragma unroll
        for (int r = 0; r < 16; ++r) {
            const int q = (r & 3) + 8 * (r >> 2) + 4 * hi;
            const float iv = __shfl(inv, q);
            #pragma unroll
            for (int half = 0; half < 2; ++half) {
                const float val = (o[half][r] + Osm[(qh * 32 + q) * 64 + half * 32 + l31]) * iv;
                out[((size_t)b * SEQ + qband + q) * DIM + h * DH + half * 32 + l31] = val;
            }
        }
    }
}

extern "C" void kernel_launch(void* const* d_in, const int* in_sizes, int n_in,
                              void* d_out, int out_size, void* d_ws, size_t ws_size,
                              hipStream_t stream)
{
    const float* x   = (const float*)d_in[0];
    // d_in[1] = mask (causal, analytic)
    const float* Wqk = (const float*)d_in[2];
    const float* Wv  = (const float*)d_in[3];
    float* out = (float*)d_out;

    // workspace: xb 8MB | qkb 4MB | vt 8MB | wcat 3MB ; qn/kn overlay xb after GEMM
    unsigned short* xb   = (unsigned short*)d_ws;
    unsigned short* qkb  = xb  + (size_t)MROWS * DIM;
    unsigned short* vt   = qkb + (size_t)MROWS * 512;
    unsigned short* wcat = vt  + (size_t)BATCH * DIM * SEQ;
    unsigned short* qn = xb;
    unsigned short* kn = xb + (size_t)MROWS * RANK;

    conv_bf16<<<4096, 256, 0, stream>>>(x,   xb,   MROWS * DIM / 4);
    conv_bf16<<<512,  256, 0, stream>>>(Wqk, wcat, 2 * RANK * DIM / 4);
    conv_bf16<<<1024, 256, 0, stream>>>(Wv,  wcat + (size_t)2 * RANK * DIM, DIM * DIM / 4);
    gemm_mfma<<<dim3(32, 24), 256, 0, stream>>>(xb, wcat, qkb, vt);
    l2norm_split<<<MROWS, 256, 0, stream>>>(qkb, qn, kn);
    attn_mfma32<<<dim3(SEQ / 64, HEADS, BATCH), 256, 0, stream>>>(qn, kn, vt, out);
}